// Round 1
// baseline (6626.291 us; speedup 1.0000x reference)
//
#include <hip/hip_runtime.h>

#define N_NODES 10000
#define N_EDGES 320000

__device__ __forceinline__ float gelu_f(float x) {
    // jax.nn.gelu approximate=True: 0.5x(1+tanh(sqrt(2/pi)(x+0.044715x^3)))
    //  = x * sigmoid(2*sqrt(2/pi)*(x+0.044715x^3))
    float x3 = x * x * x;
    return x / (1.0f + __expf(-1.5957691216057308f * (x + 0.044715f * x3)));
}

// ---------------- Kernel A: per-node linear1 (f_s, f_v) ----------------
__global__ __launch_bounds__(64) void node_l1_kernel(
    const float* __restrict__ node_input,
    const float* __restrict__ node_attr,
    const float* __restrict__ Wl1_0,   // [64][64]
    const float* __restrict__ Wl1_1,   // [32][32]
    float* __restrict__ f_s,           // [N][64]
    float* __restrict__ f_v)           // [N][96]  (w-major, c inner)
{
    const int n = blockIdx.x;
    const int t = threadIdx.x;
    __shared__ float x[160];
    const float* row = node_input + (size_t)n * 160;
    for (int i = t; i < 160; i += 64) x[i] = row[i];
    __syncthreads();
    const float a = node_attr[n];

    // f_s[t] = (xs @ Wl1_0)[t] * a/8
    float acc = 0.f;
    for (int k = 0; k < 64; ++k) acc += x[k] * Wl1_0[k * 64 + t];
    f_s[(size_t)n * 64 + t] = acc * (a * 0.125f);

    // f_v[w][c] = sum_u xv[u][c] * Wl1_1[u][w] * a/sqrt(32)
    const float sv = a * 0.17677669529663687f;
    for (int o = t; o < 96; o += 64) {
        int w = o / 3, c = o - w * 3;
        float av = 0.f;
        for (int u = 0; u < 32; ++u) av += x[64 + u * 3 + c] * Wl1_1[u * 32 + w];
        f_v[(size_t)n * 96 + o] = av * sv;
    }
}

// ---------------- Kernel B: per-edge MLP + tensor product + scatter ----------------
__global__ __launch_bounds__(128) void edge_kernel(
    const float* __restrict__ edge_attr,   // [E][4]
    const float* __restrict__ esa,         // [E][8]
    const float* __restrict__ Wfc1,        // [8][64]
    const float* __restrict__ Wfc2,        // [64][64]
    const float* __restrict__ Wfc3,        // [64][192]
    const float* __restrict__ f_s,         // [N][64]
    const float* __restrict__ f_v,         // [N][96]
    const int* __restrict__ edge_src,
    const int* __restrict__ edge_dst,
    float* __restrict__ mid)               // [N][384], pre-zeroed
{
    __shared__ float hbuf[64 * 128];       // per-thread private column hbuf[k*128+tid]
    const int tid = threadIdx.x;
    const int e = blockIdx.x * 128 + tid;
    if (e >= N_EDGES) return;

    float4 xa = ((const float4*)esa)[e * 2 + 0];
    float4 xb = ((const float4*)esa)[e * 2 + 1];
    float x[8] = {xa.x, xa.y, xa.z, xa.w, xb.x, xb.y, xb.z, xb.w};

    // ----- layer 1: h1 = gelu(esa @ Wfc1 / sqrt(8)) -> LDS -----
    for (int j = 0; j < 64; ++j) {
        float acc = 0.f;
        #pragma unroll
        for (int k = 0; k < 8; ++k) acc += x[k] * Wfc1[k * 64 + j];
        hbuf[j * 128 + tid] = gelu_f(acc * 0.35355339059327373f);
    }

    // ----- layer 2: h2 = gelu(h1 @ Wfc2 / 8) -> LDS (overwrite own column) -----
    {
        float h2[64];
        #pragma unroll
        for (int j = 0; j < 64; ++j) h2[j] = 0.f;
        for (int k = 0; k < 64; ++k) {
            float hk = hbuf[k * 128 + tid];
            const float* Wr = Wfc2 + k * 64;
            #pragma unroll
            for (int j = 0; j < 64; ++j) h2[j] += hk * Wr[j];
        }
        #pragma unroll
        for (int j = 0; j < 64; ++j) hbuf[j * 128 + tid] = gelu_f(h2[j] * 0.125f);
    }

    // per-edge data
    float4 ea = ((const float4*)edge_attr)[e];
    const float y0 = ea.x, y1a = ea.y, y1b = ea.z, y1c = ea.w;
    const int src = edge_src[e];
    const int dst = edge_dst[e];
    const float* gsrow = f_s + (size_t)src * 64;
    const float* gvrow = f_v + (size_t)src * 96;
    float* md = mid + (size_t)dst * 384;

    // ----- chunk 0: w0 = (h2 @ Wfc3[:, 0:64]) / 8 ; mid0 = w0*gs*y0 -----
    {
        float w0[64];
        #pragma unroll
        for (int j = 0; j < 64; ++j) w0[j] = 0.f;
        for (int k = 0; k < 64; ++k) {
            float hk = hbuf[k * 128 + tid];
            const float* Wr = Wfc3 + k * 192;
            #pragma unroll
            for (int j = 0; j < 64; ++j) w0[j] += hk * Wr[j];
        }
        #pragma unroll
        for (int u = 0; u < 64; ++u) {
            float g = gsrow[u];
            atomicAdd(md + u, 0.125f * w0[u] * g * y0);
        }
    }

    // ----- chunk 1: w1 = (h2 @ Wfc3[:, 64:128]) / 8 ; mid2[u][c] = w1*gs*y1[c] -----
    {
        float w1[64];
        #pragma unroll
        for (int j = 0; j < 64; ++j) w1[j] = 0.f;
        for (int k = 0; k < 64; ++k) {
            float hk = hbuf[k * 128 + tid];
            const float* Wr = Wfc3 + k * 192 + 64;
            #pragma unroll
            for (int j = 0; j < 64; ++j) w1[j] += hk * Wr[j];
        }
        #pragma unroll
        for (int u = 0; u < 64; ++u) {
            float g = gsrow[u];
            float tt = 0.125f * w1[u] * g;
            atomicAdd(md + 96 + u * 3 + 0, tt * y1a);
            atomicAdd(md + 96 + u * 3 + 1, tt * y1b);
            atomicAdd(md + 96 + u * 3 + 2, tt * y1c);
        }
    }

    // ----- chunk 2: w2 = w[128:160], w3 = w[160:192] ; mid3, mid1 -----
    {
        float w23[64];
        #pragma unroll
        for (int j = 0; j < 64; ++j) w23[j] = 0.f;
        for (int k = 0; k < 64; ++k) {
            float hk = hbuf[k * 128 + tid];
            const float* Wr = Wfc3 + k * 192 + 128;
            #pragma unroll
            for (int j = 0; j < 64; ++j) w23[j] += hk * Wr[j];
        }
        #pragma unroll
        for (int v = 0; v < 32; ++v) {
            float g0 = gvrow[v * 3 + 0];
            float g1 = gvrow[v * 3 + 1];
            float g2 = gvrow[v * 3 + 2];
            float w2v = 0.125f * w23[v];
            float w3v = 0.125f * w23[32 + v];
            float dot = g0 * y1a + g1 * y1b + g2 * y1c;
            atomicAdd(md + 64 + v, w3v * dot * 0.5773502691896258f);
            atomicAdd(md + 288 + v * 3 + 0, w2v * g0 * y0);
            atomicAdd(md + 288 + v * 3 + 1, w2v * g1 * y0);
            atomicAdd(md + 288 + v * 3 + 2, w2v * g2 * y0);
        }
    }
}

// ---------------- Kernel C: per-node linear2 + gate + self-connection ----------------
__global__ __launch_bounds__(64) void node_out_kernel(
    const float* __restrict__ node_input,
    const float* __restrict__ node_attr,
    const float* __restrict__ Wsc0,    // [64][64]
    const float* __restrict__ Wsc1,    // [32][32]
    const float* __restrict__ Wl2_s,   // [96][64]
    const float* __restrict__ Wl2_v,   // [96][32]
    const float* __restrict__ Wa,      // [96][1]
    const float* __restrict__ mid,     // [N][384]
    float* __restrict__ out)           // [N][160]
{
    const int n = blockIdx.x;
    const int t = threadIdx.x;
    __shared__ float x[160];
    __shared__ float m[384];
    const float inv = 0.17677669529663687f;  // 1/sqrt(32)
    const float* row = node_input + (size_t)n * 160;
    for (int i = t; i < 160; i += 64) x[i] = row[i];
    for (int i = t; i < 384; i += 64) m[i] = mid[(size_t)n * 384 + i] * inv;
    __syncthreads();

    const float a = node_attr[n];
    const float s96 = a * 0.10206207261596575f;  // a/sqrt(96)

    // alpha = mid_s @ Wa * a/sqrt(96)   (mid_s = [m[0:64], m[64:96]])
    float alpha = 0.f;
    for (int i = 0; i < 96; ++i) alpha += m[i] * Wa[i];
    alpha *= s96;

    // scalar outputs: lane t = channel j
    float outs = 0.f;
    for (int i = 0; i < 96; ++i) outs += m[i] * Wl2_s[i * 64 + t];
    outs *= s96;
    float scs = 0.f;
    for (int k = 0; k < 64; ++k) scs += x[k] * Wsc0[k * 64 + t];
    scs *= a * 0.125f;
    out[(size_t)n * 160 + t] = scs + alpha * outs;

    // vector outputs: o = w*3+c, o in [0,96)
    const float sv = a * 0.17677669529663687f;
    for (int o = t; o < 96; o += 64) {
        int w = o / 3, c = o - w * 3;
        float ov = 0.f;
        for (int u = 0; u < 64; ++u) ov += m[96 + u * 3 + c] * Wl2_v[u * 32 + w];
        for (int u = 0; u < 32; ++u) ov += m[288 + u * 3 + c] * Wl2_v[(64 + u) * 32 + w];
        ov *= s96;
        float scv = 0.f;
        for (int u = 0; u < 32; ++u) scv += x[64 + u * 3 + c] * Wsc1[u * 32 + w];
        scv *= sv;
        out[(size_t)n * 160 + 64 + o] = scv + alpha * ov;
    }
}

extern "C" void kernel_launch(void* const* d_in, const int* in_sizes, int n_in,
                              void* d_out, int out_size, void* d_ws, size_t ws_size,
                              hipStream_t stream) {
    const float* node_input = (const float*)d_in[0];
    const float* node_attr  = (const float*)d_in[1];
    const float* edge_attr  = (const float*)d_in[2];
    const float* esa        = (const float*)d_in[3];
    const float* Wsc0       = (const float*)d_in[4];
    const float* Wsc1       = (const float*)d_in[5];
    const float* Wl1_0      = (const float*)d_in[6];
    const float* Wl1_1      = (const float*)d_in[7];
    const float* Wfc1       = (const float*)d_in[8];
    const float* Wfc2       = (const float*)d_in[9];
    const float* Wfc3       = (const float*)d_in[10];
    const float* Wl2_s      = (const float*)d_in[11];
    const float* Wl2_v      = (const float*)d_in[12];
    const float* Wa         = (const float*)d_in[13];
    const int* edge_src     = (const int*)d_in[14];
    const int* edge_dst     = (const int*)d_in[15];
    float* out = (float*)d_out;

    float* ws  = (float*)d_ws;
    float* f_s = ws;                       // N*64
    float* f_v = ws + (size_t)N_NODES * 64;  // N*96
    float* mid = ws + (size_t)N_NODES * 160; // N*384

    // atomics accumulate -> must zero every call
    hipMemsetAsync(mid, 0, (size_t)N_NODES * 384 * sizeof(float), stream);

    node_l1_kernel<<<N_NODES, 64, 0, stream>>>(node_input, node_attr, Wl1_0, Wl1_1, f_s, f_v);
    edge_kernel<<<N_EDGES / 128, 128, 0, stream>>>(edge_attr, esa, Wfc1, Wfc2, Wfc3,
                                                   f_s, f_v, edge_src, edge_dst, mid);
    node_out_kernel<<<N_NODES, 64, 0, stream>>>(node_input, node_attr, Wsc0, Wsc1,
                                                Wl2_s, Wl2_v, Wa, mid, out);
}

// Round 2
// 646.789 us; speedup vs baseline: 10.2449x; 10.2449x over previous
//
#include <hip/hip_runtime.h>

#define N_NODES 10000
#define N_EDGES 320000
#define INV3 0.5773502691896258f

__device__ __forceinline__ float gelu_f(float x) {
    // jax.nn.gelu approximate=True
    float x3 = x * x * x;
    return x / (1.0f + __expf(-1.5957691216057308f * (x + 0.044715f * x3)));
}

// ---------------- CSR build ----------------
__global__ __launch_bounds__(256) void hist_kernel(const int* __restrict__ dst, int* __restrict__ deg) {
    int e = blockIdx.x * 256 + threadIdx.x;
    if (e < N_EDGES) atomicAdd(&deg[dst[e]], 1);
}

__global__ __launch_bounds__(256) void scan_kernel(const int* __restrict__ deg,
                                                   int* __restrict__ rowptr,
                                                   int* __restrict__ cursor) {
    __shared__ int part[256];
    const int t = threadIdx.x;
    const int base = t * 40;
    int s = 0;
    for (int i = 0; i < 40; ++i) {
        int idx = base + i;
        if (idx < N_NODES) s += deg[idx];
    }
    part[t] = s;
    __syncthreads();
    for (int o = 1; o < 256; o <<= 1) {
        int v = (t >= o) ? part[t - o] : 0;
        __syncthreads();
        part[t] += v;
        __syncthreads();
    }
    int run = (t == 0) ? 0 : part[t - 1];
    for (int i = 0; i < 40; ++i) {
        int idx = base + i;
        if (idx < N_NODES) {
            int d = deg[idx];
            rowptr[idx] = run;
            cursor[idx] = run;
            run += d;
        } else if (idx == N_NODES) {
            rowptr[idx] = run;
        }
    }
}

__global__ __launch_bounds__(256) void scatter_kernel(const int* __restrict__ dst,
                                                      int* __restrict__ cursor,
                                                      int* __restrict__ elist) {
    int e = blockIdx.x * 256 + threadIdx.x;
    if (e < N_EDGES) {
        int p = atomicAdd(&cursor[dst[e]], 1);
        elist[p] = e;
    }
}

// ---------------- Kernel A: per-node linear1 (f_s, f_v) ----------------
__global__ __launch_bounds__(64) void node_l1_kernel(
    const float* __restrict__ node_input,
    const float* __restrict__ node_attr,
    const float* __restrict__ Wl1_0,
    const float* __restrict__ Wl1_1,
    float* __restrict__ f_s,
    float* __restrict__ f_v)
{
    const int n = blockIdx.x;
    const int t = threadIdx.x;
    __shared__ float x[160];
    const float* row = node_input + (size_t)n * 160;
    for (int i = t; i < 160; i += 64) x[i] = row[i];
    __syncthreads();
    const float a = node_attr[n];

    float acc = 0.f;
    for (int k = 0; k < 64; ++k) acc += x[k] * Wl1_0[k * 64 + t];
    f_s[(size_t)n * 64 + t] = acc * (a * 0.125f);

    const float sv = a * 0.17677669529663687f;
    for (int o = t; o < 96; o += 64) {
        int w = o / 3, c = o - w * 3;
        float av = 0.f;
        for (int u = 0; u < 32; ++u) av += x[64 + u * 3 + c] * Wl1_1[u * 32 + w];
        f_v[(size_t)n * 96 + o] = av * sv;
    }
}

// ---------------- Kernel B: sorted edges, MLP + TP + segmented-reduce scatter ----------------
#define SEGSTEP(v, a, m) { float u_ = __int_as_float(__builtin_amdgcn_ds_bpermute((a), __float_as_int(v))); (v) += u_ * (m); }
#define SEGSCAN(v) { SEGSTEP(v, a1, m1) SEGSTEP(v, a2, m2) SEGSTEP(v, a4, m4) SEGSTEP(v, a8, m8) SEGSTEP(v, a16, m16) SEGSTEP(v, a32, m32) }

__global__ __launch_bounds__(128) void edge_kernel(
    const float* __restrict__ edge_attr,   // [E][4]
    const float* __restrict__ esa,         // [E][8]
    const float* __restrict__ Wfc1,        // [8][64]
    const float* __restrict__ Wfc2,        // [64][64]
    const float* __restrict__ Wfc3,        // [64][192]
    const float* __restrict__ f_s,         // [N][64]
    const float* __restrict__ f_v,         // [N][96]
    const int* __restrict__ edge_src,
    const int* __restrict__ edge_dst,
    const int* __restrict__ elist,         // dst-sorted edge ids
    float* __restrict__ mid)               // [N][384], pre-zeroed
{
    __shared__ float hbuf[64 * 128];
    const int tid = threadIdx.x;
    const int lane = tid & 63;
    const int s = blockIdx.x * 128 + tid;
    const int e = elist[s];

    float4 xa = ((const float4*)esa)[e * 2 + 0];
    float4 xb = ((const float4*)esa)[e * 2 + 1];
    float x[8] = {xa.x, xa.y, xa.z, xa.w, xb.x, xb.y, xb.z, xb.w};

    // layer 1 -> LDS (per-thread private column)
    for (int j = 0; j < 64; ++j) {
        float acc = 0.f;
        #pragma unroll
        for (int k = 0; k < 8; ++k) acc += x[k] * Wfc1[k * 64 + j];
        hbuf[j * 128 + tid] = gelu_f(acc * 0.35355339059327373f);
    }
    // layer 2
    {
        float h2[64];
        #pragma unroll
        for (int j = 0; j < 64; ++j) h2[j] = 0.f;
        for (int k = 0; k < 64; ++k) {
            float hk = hbuf[k * 128 + tid];
            const float* Wr = Wfc2 + k * 64;
            #pragma unroll
            for (int j = 0; j < 64; ++j) h2[j] += hk * Wr[j];
        }
        #pragma unroll
        for (int j = 0; j < 64; ++j) hbuf[j * 128 + tid] = gelu_f(h2[j] * 0.125f);
    }

    const int src = edge_src[e];
    const int mydst = edge_dst[e];
    float4 ea = ((const float4*)edge_attr)[e];
    const float y0 = ea.x, y1a = ea.y, y1b = ea.z, y1c = ea.w;
    const float* gsrow = f_s + (size_t)src * 64;
    const float* gvrow = f_v + (size_t)src * 96;
    float* md = mid + (size_t)mydst * 384;

    // ---- per-wave segment info (edges sorted by dst) ----
    int up = __shfl_up(mydst, 1);
    bool is_head = (lane == 0) || (up != mydst);
    int dn = __shfl_down(mydst, 1);
    const bool is_tail = (lane == 63) || (dn != mydst);
    unsigned long long hb = __ballot(is_head);
    unsigned long long lowmask = (~0ull) >> (63 - lane);
    int H = 63 - __clzll(hb & lowmask);   // last head at or below my lane
    int dist = lane - H;
    const float m1  = dist >= 1  ? 1.f : 0.f;
    const float m2  = dist >= 2  ? 1.f : 0.f;
    const float m4  = dist >= 4  ? 1.f : 0.f;
    const float m8  = dist >= 8  ? 1.f : 0.f;
    const float m16 = dist >= 16 ? 1.f : 0.f;
    const float m32 = dist >= 32 ? 1.f : 0.f;
    const int a1  = ((lane - 1)  & 63) * 4;
    const int a2  = ((lane - 2)  & 63) * 4;
    const int a4  = ((lane - 4)  & 63) * 4;
    const int a8  = ((lane - 8)  & 63) * 4;
    const int a16 = ((lane - 16) & 63) * 4;
    const int a32 = ((lane - 32) & 63) * 4;

    // ---- PASS A: w0 -> mid[0:64] = 0.125*w0*gs*y0 ----
    #pragma unroll 1
    for (int jg = 0; jg < 4; ++jg) {
        float acc[16];
        #pragma unroll
        for (int i = 0; i < 16; ++i) acc[i] = 0.f;
        const float* W = Wfc3 + jg * 16;
        for (int k = 0; k < 64; ++k) {
            float hk = hbuf[k * 128 + tid];
            #pragma unroll
            for (int i = 0; i < 16; ++i) acc[i] += hk * W[k * 192 + i];
        }
        #pragma unroll
        for (int i = 0; i < 16; ++i) {
            acc[i] = 0.125f * acc[i] * gsrow[jg * 16 + i] * y0;
            SEGSCAN(acc[i]);
        }
        if (is_tail) {
            #pragma unroll
            for (int i = 0; i < 16; ++i) atomicAdd(md + jg * 16 + i, acc[i]);
        }
    }

    // ---- PASS B: w1 -> mid[96 + u*3 + c] = 0.125*w1*gs*y1[c] ----
    #pragma unroll 1
    for (int jg = 0; jg < 4; ++jg) {
        float acc[16];
        #pragma unroll
        for (int i = 0; i < 16; ++i) acc[i] = 0.f;
        const float* W = Wfc3 + 64 + jg * 16;
        for (int k = 0; k < 64; ++k) {
            float hk = hbuf[k * 128 + tid];
            #pragma unroll
            for (int i = 0; i < 16; ++i) acc[i] += hk * W[k * 192 + i];
        }
        float cB[16], cC[16];
        #pragma unroll
        for (int i = 0; i < 16; ++i) {
            float tt = 0.125f * acc[i] * gsrow[jg * 16 + i];
            acc[i] = tt * y1a; cB[i] = tt * y1b; cC[i] = tt * y1c;
            SEGSCAN(acc[i]); SEGSCAN(cB[i]); SEGSCAN(cC[i]);
        }
        if (is_tail) {
            #pragma unroll
            for (int i = 0; i < 16; ++i) {
                int u = jg * 16 + i;
                atomicAdd(md + 96 + u * 3 + 0, acc[i]);
                atomicAdd(md + 96 + u * 3 + 1, cB[i]);
                atomicAdd(md + 96 + u * 3 + 2, cC[i]);
            }
        }
    }

    // ---- PASS C: w2 -> mid[288 + u*3 + c] = 0.125*w2*gv[u][c]*y0 ----
    #pragma unroll 1
    for (int jg = 0; jg < 2; ++jg) {
        float acc[16];
        #pragma unroll
        for (int i = 0; i < 16; ++i) acc[i] = 0.f;
        const float* W = Wfc3 + 128 + jg * 16;
        for (int k = 0; k < 64; ++k) {
            float hk = hbuf[k * 128 + tid];
            #pragma unroll
            for (int i = 0; i < 16; ++i) acc[i] += hk * W[k * 192 + i];
        }
        float cB[16], cC[16];
        #pragma unroll
        for (int i = 0; i < 16; ++i) {
            int u = jg * 16 + i;
            float w2v = 0.125f * acc[i] * y0;
            acc[i] = w2v * gvrow[u * 3 + 0];
            cB[i]  = w2v * gvrow[u * 3 + 1];
            cC[i]  = w2v * gvrow[u * 3 + 2];
            SEGSCAN(acc[i]); SEGSCAN(cB[i]); SEGSCAN(cC[i]);
        }
        if (is_tail) {
            #pragma unroll
            for (int i = 0; i < 16; ++i) {
                int u = jg * 16 + i;
                atomicAdd(md + 288 + u * 3 + 0, acc[i]);
                atomicAdd(md + 288 + u * 3 + 1, cB[i]);
                atomicAdd(md + 288 + u * 3 + 2, cC[i]);
            }
        }
    }

    // ---- PASS D: w3 -> mid[64 + u] = 0.125*w3*(gv[u].y1)*INV3 ----
    #pragma unroll 1
    for (int jg = 0; jg < 2; ++jg) {
        float acc[16];
        #pragma unroll
        for (int i = 0; i < 16; ++i) acc[i] = 0.f;
        const float* W = Wfc3 + 160 + jg * 16;
        for (int k = 0; k < 64; ++k) {
            float hk = hbuf[k * 128 + tid];
            #pragma unroll
            for (int i = 0; i < 16; ++i) acc[i] += hk * W[k * 192 + i];
        }
        #pragma unroll
        for (int i = 0; i < 16; ++i) {
            int u = jg * 16 + i;
            float dot = gvrow[u * 3 + 0] * y1a + gvrow[u * 3 + 1] * y1b + gvrow[u * 3 + 2] * y1c;
            acc[i] = 0.125f * acc[i] * dot * INV3;
            SEGSCAN(acc[i]);
        }
        if (is_tail) {
            #pragma unroll
            for (int i = 0; i < 16; ++i) atomicAdd(md + 64 + jg * 16 + i, acc[i]);
        }
    }
}

// ---------------- Kernel C: per-node linear2 + gate + self-connection ----------------
__global__ __launch_bounds__(64) void node_out_kernel(
    const float* __restrict__ node_input,
    const float* __restrict__ node_attr,
    const float* __restrict__ Wsc0,
    const float* __restrict__ Wsc1,
    const float* __restrict__ Wl2_s,
    const float* __restrict__ Wl2_v,
    const float* __restrict__ Wa,
    const float* __restrict__ mid,
    float* __restrict__ out)
{
    const int n = blockIdx.x;
    const int t = threadIdx.x;
    __shared__ float x[160];
    __shared__ float m[384];
    const float inv = 0.17677669529663687f;  // 1/sqrt(NUM_NEIGHBORS)
    const float* row = node_input + (size_t)n * 160;
    for (int i = t; i < 160; i += 64) x[i] = row[i];
    for (int i = t; i < 384; i += 64) m[i] = mid[(size_t)n * 384 + i] * inv;
    __syncthreads();

    const float a = node_attr[n];
    const float s96 = a * 0.10206207261596575f;

    float alpha = 0.f;
    for (int i = 0; i < 96; ++i) alpha += m[i] * Wa[i];
    alpha *= s96;

    float outs = 0.f;
    for (int i = 0; i < 96; ++i) outs += m[i] * Wl2_s[i * 64 + t];
    outs *= s96;
    float scs = 0.f;
    for (int k = 0; k < 64; ++k) scs += x[k] * Wsc0[k * 64 + t];
    scs *= a * 0.125f;
    out[(size_t)n * 160 + t] = scs + alpha * outs;

    const float sv = a * 0.17677669529663687f;
    for (int o = t; o < 96; o += 64) {
        int w = o / 3, c = o - w * 3;
        float ov = 0.f;
        for (int u = 0; u < 64; ++u) ov += m[96 + u * 3 + c] * Wl2_v[u * 32 + w];
        for (int u = 0; u < 32; ++u) ov += m[288 + u * 3 + c] * Wl2_v[(64 + u) * 32 + w];
        ov *= s96;
        float scv = 0.f;
        for (int u = 0; u < 32; ++u) scv += x[64 + u * 3 + c] * Wsc1[u * 32 + w];
        scv *= sv;
        out[(size_t)n * 160 + 64 + o] = scv + alpha * ov;
    }
}

extern "C" void kernel_launch(void* const* d_in, const int* in_sizes, int n_in,
                              void* d_out, int out_size, void* d_ws, size_t ws_size,
                              hipStream_t stream) {
    const float* node_input = (const float*)d_in[0];
    const float* node_attr  = (const float*)d_in[1];
    const float* edge_attr  = (const float*)d_in[2];
    const float* esa        = (const float*)d_in[3];
    const float* Wsc0       = (const float*)d_in[4];
    const float* Wsc1       = (const float*)d_in[5];
    const float* Wl1_0      = (const float*)d_in[6];
    const float* Wl1_1      = (const float*)d_in[7];
    const float* Wfc1       = (const float*)d_in[8];
    const float* Wfc2       = (const float*)d_in[9];
    const float* Wfc3       = (const float*)d_in[10];
    const float* Wl2_s      = (const float*)d_in[11];
    const float* Wl2_v      = (const float*)d_in[12];
    const float* Wa         = (const float*)d_in[13];
    const int* edge_src     = (const int*)d_in[14];
    const int* edge_dst     = (const int*)d_in[15];
    float* out = (float*)d_out;

    float* ws  = (float*)d_ws;
    float* f_s = ws;                          // N*64
    float* f_v = ws + (size_t)N_NODES * 64;   // N*96
    float* mid = ws + (size_t)N_NODES * 160;  // N*384

    // CSR scratch lives in d_out (dead until node_out_kernel overwrites it)
    int* ibuf   = (int*)d_out;
    int* deg    = ibuf;            // [0, 10000)
    int* rowptr = ibuf + 10016;    // 10001 entries
    int* cursor = ibuf + 20032;    // 10000 entries
    int* elist  = ibuf + 30080;    // 320000 entries -> end 350080 < 1.6M floats

    hipMemsetAsync(deg, 0, (size_t)N_NODES * sizeof(int), stream);
    hipMemsetAsync(mid, 0, (size_t)N_NODES * 384 * sizeof(float), stream);

    hist_kernel<<<(N_EDGES + 255) / 256, 256, 0, stream>>>(edge_dst, deg);
    scan_kernel<<<1, 256, 0, stream>>>(deg, rowptr, cursor);
    scatter_kernel<<<(N_EDGES + 255) / 256, 256, 0, stream>>>(edge_dst, cursor, elist);

    node_l1_kernel<<<N_NODES, 64, 0, stream>>>(node_input, node_attr, Wl1_0, Wl1_1, f_s, f_v);
    edge_kernel<<<N_EDGES / 128, 128, 0, stream>>>(edge_attr, esa, Wfc1, Wfc2, Wfc3,
                                                   f_s, f_v, edge_src, edge_dst, elist, mid);
    node_out_kernel<<<N_NODES, 64, 0, stream>>>(node_input, node_attr, Wsc0, Wsc1,
                                                Wl2_s, Wl2_v, Wa, mid, out);
}